// Round 1
// baseline (667.825 us; speedup 1.0000x reference)
//
#include <hip/hip_runtime.h>
#include <hip/hip_bf16.h>

// Fused masked SDPA: B=64, LQ=LK=1024, D=64, temperature=8.
// R4: LDS-free K/V paths. K and V are L2-resident (256 KB/batch), so MFMA
// B-frags are loaded per-lane directly from global (same pattern as the Q
// A-frags), eliminating the K/V LDS staging, its conversions and all its
// bank conflicts. Softmax restructured from online to max-then-sum over the
// registered scores: one exp pass (stored, reused in pass 2 as p = e*Cr),
// ~70 transcendentals/lane instead of ~224. bf16 via hw v_cvt (__bf16
// casts), Q pre-scaled by 1/8 (exact in bf16). Nontemporal MSK loads and
// P/AV stores keep K/V hot in L2. LDS keeps only: P transpose slice
// (wave-private, barrier-free), softmax stats, final O reduction.

#define NB   64
#define SLQ  1024
#define SLK  1024
#define DH   64
#define TQ   16
#define TK   64
#define NKT  16
#define PSTR 40   // P slice row stride (u16): 80B, 16B-aligned for b128
#define OSTR 68   // O partial row stride (f32): +4 pad spreads banks

typedef __attribute__((ext_vector_type(4))) float          f32x4;
typedef __attribute__((ext_vector_type(8))) __bf16         bf16x8;
typedef __attribute__((ext_vector_type(8))) unsigned short u16x8;

static __device__ __forceinline__ unsigned short f2bf(float f) {
  return __builtin_bit_cast(unsigned short, (__bf16)f);   // hw cvt, RTNE
}
static __device__ __forceinline__ bf16x8 cvt8(f32x4 a, f32x4 b) {
  bf16x8 r;
#pragma unroll
  for (int i = 0; i < 4; ++i) { r[i] = (__bf16)a[i]; r[i + 4] = (__bf16)b[i]; }
  return r;
}

__global__ __launch_bounds__(256, 3) void sdpa_fused(
    const float* __restrict__ Q, const float* __restrict__ K,
    const float* __restrict__ V, const int* __restrict__ QM,
    const int* __restrict__ KM, const int* __restrict__ MSK,
    float* __restrict__ OUT_AV, float* __restrict__ OUT_P) {
  // XCD swizzle: co-schedule same-batch blocks on one XCD for K/V L2 reuse
  const int g    = blockIdx.x;
  const int slot = g >> 3;
  const int b    = ((slot >> 6) << 3) | (g & 7);
  const int q0   = (slot & 63) * TQ;

  const int tid  = threadIdx.x;
  const int wave = tid >> 6;
  const int lane = tid & 63;
  const int col  = lane & 15;
  const int quad = lane >> 4;

  // LDS: [0,17408) per-wave O partials (16 x OSTR f32),
  //      [17408,22528) per-wave P slices (16 x PSTR u16),
  //      [22528,23168) softmax stats.
  __shared__ __align__(16) unsigned char RAW[23168];
  float*          Ow = (float*)RAW + wave * (16 * OSTR);
  unsigned short* Pw = (unsigned short*)(RAW + 17408) + wave * (16 * PSTR);
  float* partM = (float*)(RAW + 22528);
  float* partL = partM + 64;
  float* rowM  = partL + 64;
  float* rowS  = rowM + 16;

  const size_t mbase = ((size_t)b * SLQ + q0) * SLK;

  // ---- Q A-frags from global, pre-scaled by 1/8 (exact exponent shift) ----
  const float* qp = Q + ((size_t)b * SLQ + q0 + col) * DH + quad * 8;
  bf16x8 aq0, aq1;
  {
    f32x4 a = *(const f32x4*)qp        * 0.125f;
    f32x4 c = *(const f32x4*)(qp + 4)  * 0.125f;
    f32x4 d = *(const f32x4*)(qp + 32) * 0.125f;
    f32x4 e = *(const f32x4*)(qp + 36) * 0.125f;
    aq0 = cvt8(a, c);
    aq1 = cvt8(d, e);
  }

  // =================== Pass 1: S = (Q/8)K^T, direct-global K frags =========
  const float* kp  = K + ((size_t)b * SLK + wave * 16 + col) * DH + quad * 8;
  const int*   kmp = KM + b * SLK + wave * 16 + col;
  const int*   mkp = MSK + mbase + (size_t)(quad * 4) * SLK + wave * 16 + col;

  float sreg[NKT][4];
#pragma unroll
  for (int kt = 0; kt < NKT; ++kt) {
    const float* kq = kp + (size_t)kt * (TK * DH);
    f32x4 k0 = *(const f32x4*)kq;
    f32x4 k1 = *(const f32x4*)(kq + 4);
    f32x4 k2 = *(const f32x4*)(kq + 32);
    f32x4 k3 = *(const f32x4*)(kq + 36);
    const int km = kmp[kt * TK];
    int mr[4];
#pragma unroll
    for (int r = 0; r < 4; ++r)
      mr[r] = __builtin_nontemporal_load(mkp + (size_t)r * SLK + kt * TK);
    bf16x8 bk0 = cvt8(k0, k1);
    bf16x8 bk1 = cvt8(k2, k3);
    f32x4 acc = {0.f, 0.f, 0.f, 0.f};
    acc = __builtin_amdgcn_mfma_f32_16x16x32_bf16(aq0, bk0, acc, 0, 0, 0);
    acc = __builtin_amdgcn_mfma_f32_16x16x32_bf16(aq1, bk1, acc, 0, 0, 0);
#pragma unroll
    for (int r = 0; r < 4; ++r)
      sreg[kt][r] = (km && mr[r]) ? acc[r] : -INFINITY;
  }

  // ====== stats: max over registers -> butterfly -> one exp pass -> sum ====
  float Mw[4], Cr[4];
#pragma unroll
  for (int r = 0; r < 4; ++r) {
    float m = sreg[0][r];
#pragma unroll
    for (int kt = 1; kt < NKT; ++kt) m = fmaxf(m, sreg[kt][r]);
#pragma unroll
    for (int off = 1; off < 16; off <<= 1) m = fmaxf(m, __shfl_xor(m, off, 64));
    Mw[r] = m;
    const float mc = fmaxf(m, -1e30f);   // all-masked guard: exp(-inf-mc)=0
    float l = 0.f;
#pragma unroll
    for (int kt = 0; kt < NKT; ++kt) {
      float e = __expf(sreg[kt][r] - mc);
      sreg[kt][r] = e;                   // reuse in pass 2: p = e * Cr
      l += e;
    }
#pragma unroll
    for (int off = 1; off < 16; off <<= 1) l += __shfl_xor(l, off, 64);
    if (col == 0) {
      partM[wave * 16 + quad * 4 + r] = Mw[r];
      partL[wave * 16 + quad * 4 + r] = l;
    }
  }
  __syncthreads();
  if (tid < TQ) {
    float M = -INFINITY, L = 0.f;
#pragma unroll
    for (int w = 0; w < 4; ++w) {
      float m_ = partM[w * 16 + tid], l_ = partL[w * 16 + tid];
      float mn = fmaxf(M, m_);
      if (mn != -INFINITY) {
        L = L * __expf(M - mn) + l_ * __expf(m_ - mn);
        M = mn;
      }
    }
    rowM[tid] = fmaxf(M, -1e30f);
    rowS[tid] = (QM[b * SLQ + q0 + tid] && L > 0.f) ? (1.f / L) : 0.f;
  }
  __syncthreads();
#pragma unroll
  for (int r = 0; r < 4; ++r)
    Cr[r] = __expf(fmaxf(Mw[r], -1e30f) - rowM[quad * 4 + r]) * rowS[quad * 4 + r];

  // ====== Pass 2: p = e*Cr, P write + transpose via LDS, direct-global V ===
  // V B-frag: local key kk = quad*8+j -> global row
  //   st*128 + (quad>>1)*64 + wave*16 + (quad&1)*8 + j, column n0*16+col.
  const float* vp = V + ((size_t)b * SLK + wave * 16 + (quad & 1) * 8 +
                         (quad >> 1) * TK) * DH + col;
  float* outp = OUT_P + mbase + (size_t)(quad * 4) * SLK + wave * 16 + col;

  f32x4 acco[4] = {{0.f,0.f,0.f,0.f},{0.f,0.f,0.f,0.f},
                   {0.f,0.f,0.f,0.f},{0.f,0.f,0.f,0.f}};
#pragma unroll
  for (int st = 0; st < 8; ++st) {
    const int kt0 = st * 2, kt1 = kt0 + 1;
    float p0[4], p1[4];
#pragma unroll
    for (int r = 0; r < 4; ++r) {
      p0[r] = sreg[kt0][r] * Cr[r];
      p1[r] = sreg[kt1][r] * Cr[r];
      Pw[(quad * 4 + r) * PSTR + col]      = f2bf(p0[r]);
      Pw[(quad * 4 + r) * PSTR + 16 + col] = f2bf(p1[r]);
    }
#pragma unroll
    for (int r = 0; r < 4; ++r) {
      __builtin_nontemporal_store(p0[r], outp + (size_t)r * SLK + kt0 * TK);
      __builtin_nontemporal_store(p1[r], outp + (size_t)r * SLK + kt1 * TK);
    }

    // V frags direct from global (L2-hit), issued before the ap LDS wait
    const float* vq = vp + (size_t)st * (2 * TK * DH);
    float vv[4][8];
#pragma unroll
    for (int n0 = 0; n0 < 4; ++n0)
#pragma unroll
      for (int j = 0; j < 8; ++j)
        vv[n0][j] = vq[(size_t)j * DH + n0 * 16];

    // A = P[q=col][kk=quad*8+j] via wave-private LDS transpose
    bf16x8 ap = __builtin_bit_cast(bf16x8, *(const u16x8*)&Pw[col * PSTR + quad * 8]);
#pragma unroll
    for (int n0 = 0; n0 < 4; ++n0) {
      bf16x8 bv;
#pragma unroll
      for (int j = 0; j < 8; ++j) bv[j] = (__bf16)vv[n0][j];
      acco[n0] = __builtin_amdgcn_mfma_f32_16x16x32_bf16(ap, bv, acco[n0], 0, 0, 0);
    }
  }

  // ====== final O: per-wave partial -> LDS -> cross-wave reduce ============
#pragma unroll
  for (int n0 = 0; n0 < 4; ++n0)
#pragma unroll
    for (int r = 0; r < 4; ++r)
      Ow[(quad * 4 + r) * OSTR + n0 * 16 + col] = acco[n0][r];
  __syncthreads();
  {
    const int qq = tid >> 4, dd = (tid & 15) * 4;
    f32x4 s = {0.f, 0.f, 0.f, 0.f};
#pragma unroll
    for (int w = 0; w < 4; ++w) {
      const float* Os = (const float*)RAW + w * (16 * OSTR);
      s += *(const f32x4*)&Os[qq * OSTR + dd];
    }
    __builtin_nontemporal_store(s, (f32x4*)&OUT_AV[((size_t)b * SLQ + q0 + qq) * DH + dd]);
  }
}

extern "C" void kernel_launch(void* const* d_in, const int* in_sizes, int n_in,
                              void* d_out, int out_size, void* d_ws, size_t ws_size,
                              hipStream_t stream) {
  const float* q  = (const float*)d_in[0];
  const float* k  = (const float*)d_in[1];
  const float* v  = (const float*)d_in[2];
  const int*   qm = (const int*)d_in[3];
  const int*   km = (const int*)d_in[4];
  const int*   mk = (const int*)d_in[5];
  float* out_av = (float*)d_out;                          // [B,LQ,D]
  float* out_p  = out_av + (size_t)NB * SLQ * DH;         // [B,LQ,LK]
  sdpa_fused<<<dim3(NB * (SLQ / TQ)), dim3(256), 0, stream>>>(q, k, v, qm, km, mk, out_av, out_p);
}

// Round 2
// 625.430 us; speedup vs baseline: 1.0678x; 1.0678x over previous
//
#include <hip/hip_runtime.h>
#include <hip/hip_bf16.h>

// Fused masked SDPA: B=64, LQ=LK=1024, D=64, temperature=8.
// R5 = R4 pass-1 + R3 pass-2, no nontemporal stores.
//  - Pass 1: direct-global K B-frags (vectorized f32x4, no LDS), registered
//    S, max-then-sum softmax with ONE exp pass (e stored, reused as p=e*Cr).
//  - Pass 2: V staged through wave-private LDS slice (coalesced dwordx4
//    global loads, prefetched one step ahead; scalar u16 column reads at
//    <=2-way conflict with VSTR=76) -- reverting R4's scalar global V
//    gathers, which were L2-latency-bound.
//  - All stores plain write-back: R4's nontemporal P stores caused partial
//    line RMW (+70MB write, +15MB fetch HBM traffic).
//  - hw v_cvt bf16 everywhere, Q pre-scaled by 1/8 (exact).

#define NB   64
#define SLQ  1024
#define SLK  1024
#define DH   64
#define TQ   16
#define TK   64
#define NKT  16
#define VSTR 76   // V slice row stride (u16): 152B -> column reads 2-way max
#define PSTR 40   // P slice row stride (u16): 80B, 16B-aligned for b128
#define OSTR 68   // O partial row stride (f32): 2-way max on writes

typedef __attribute__((ext_vector_type(4))) float          f32x4;
typedef __attribute__((ext_vector_type(8))) __bf16         bf16x8;
typedef __attribute__((ext_vector_type(8))) unsigned short u16x8;
typedef __attribute__((ext_vector_type(4))) unsigned short u16x4;

static __device__ __forceinline__ unsigned short f2bf(float f) {
  return __builtin_bit_cast(unsigned short, (__bf16)f);   // hw cvt, RTNE
}
static __device__ __forceinline__ bf16x8 cvt8(f32x4 a, f32x4 b) {
  bf16x8 r;
#pragma unroll
  for (int i = 0; i < 4; ++i) { r[i] = (__bf16)a[i]; r[i + 4] = (__bf16)b[i]; }
  return r;
}
static __device__ __forceinline__ u16x4 cvt4(f32x4 v) {
  u16x4 h;
#pragma unroll
  for (int i = 0; i < 4; ++i) h[i] = f2bf(v[i]);
  return h;
}

__global__ __launch_bounds__(256, 3) void sdpa_fused(
    const float* __restrict__ Q, const float* __restrict__ K,
    const float* __restrict__ V, const int* __restrict__ QM,
    const int* __restrict__ KM, const int* __restrict__ MSK,
    float* __restrict__ OUT_AV, float* __restrict__ OUT_P) {
  // XCD swizzle: co-schedule same-batch blocks on one XCD for K/V L2 reuse
  const int g    = blockIdx.x;
  const int slot = g >> 3;
  const int b    = ((slot >> 6) << 3) | (g & 7);
  const int q0   = (slot & 63) * TQ;

  const int tid  = threadIdx.x;
  const int wave = tid >> 6;
  const int lane = tid & 63;
  const int col  = lane & 15;
  const int quad = lane >> 4;
  const int lrow = quad;             // staging row subgroup
  const int lc4  = col * 4;          // staging column (x4 elements)

  // LDS: [0,19456): per-wave union of V slice (4864 B) / O partial (4352 B)
  //      [19456,24576): per-wave P slice (1280 B)
  //      [24576,25216): softmax stats
  __shared__ __align__(16) unsigned char RAW[25216];
  unsigned short* Vw = (unsigned short*)(RAW + wave * (32 * VSTR * 2));
  float*          Ow = (float*)(RAW + wave * (32 * VSTR * 2));
  unsigned short* Pw = (unsigned short*)(RAW + 19456) + wave * (16 * PSTR);
  float* partM = (float*)(RAW + 24576);
  float* partL = partM + 64;
  float* rowM  = partL + 64;
  float* rowS  = rowM + 16;

  const size_t mbase = ((size_t)b * SLQ + q0) * SLK;
  const f32x4* vb4 = (const f32x4*)(V + (size_t)b * SLK * DH);

  // ---- Q A-frags from global, pre-scaled by 1/8 (exact exponent shift) ----
  const float* qp = Q + ((size_t)b * SLQ + q0 + col) * DH + quad * 8;
  bf16x8 aq0, aq1;
  {
    f32x4 a = *(const f32x4*)qp        * 0.125f;
    f32x4 c = *(const f32x4*)(qp + 4)  * 0.125f;
    f32x4 d = *(const f32x4*)(qp + 32) * 0.125f;
    f32x4 e = *(const f32x4*)(qp + 36) * 0.125f;
    aq0 = cvt8(a, c);
    aq1 = cvt8(d, e);
  }

  // =================== Pass 1: S = (Q/8)K^T, direct-global K frags =========
  const float* kp  = K + ((size_t)b * SLK + wave * 16 + col) * DH + quad * 8;
  const int*   kmp = KM + b * SLK + wave * 16 + col;
  const int*   mkp = MSK + mbase + (size_t)(quad * 4) * SLK + wave * 16 + col;

  float sreg[NKT][4];
#pragma unroll
  for (int kt = 0; kt < NKT; ++kt) {
    const float* kq = kp + (size_t)kt * (TK * DH);
    f32x4 k0 = *(const f32x4*)kq;
    f32x4 k1 = *(const f32x4*)(kq + 4);
    f32x4 k2 = *(const f32x4*)(kq + 32);
    f32x4 k3 = *(const f32x4*)(kq + 36);
    const int km = kmp[kt * TK];
    int mr[4];
#pragma unroll
    for (int r = 0; r < 4; ++r) mr[r] = mkp[(size_t)r * SLK + kt * TK];
    bf16x8 bk0 = cvt8(k0, k1);
    bf16x8 bk1 = cvt8(k2, k3);
    f32x4 acc = {0.f, 0.f, 0.f, 0.f};
    acc = __builtin_amdgcn_mfma_f32_16x16x32_bf16(aq0, bk0, acc, 0, 0, 0);
    acc = __builtin_amdgcn_mfma_f32_16x16x32_bf16(aq1, bk1, acc, 0, 0, 0);
#pragma unroll
    for (int r = 0; r < 4; ++r)
      sreg[kt][r] = (km && mr[r]) ? acc[r] : -INFINITY;
  }

  // prefetch V step 0 (2 tiles x this wave's 16 rows) during stats phase
  f32x4 vreg[8];
#pragma unroll
  for (int j = 0; j < 8; ++j)
    vreg[j] = vb4[(size_t)((j >> 2) * TK + wave * 16 + (j & 3) * 4 + lrow) * 16 + col];

  // ====== stats: max over registers -> butterfly -> one exp pass -> sum ====
  float Mw[4], Cr[4];
#pragma unroll
  for (int r = 0; r < 4; ++r) {
    float m = sreg[0][r];
#pragma unroll
    for (int kt = 1; kt < NKT; ++kt) m = fmaxf(m, sreg[kt][r]);
#pragma unroll
    for (int off = 1; off < 16; off <<= 1) m = fmaxf(m, __shfl_xor(m, off, 64));
    Mw[r] = m;
    const float mc = fmaxf(m, -1e30f);   // all-masked guard: exp(-inf-mc)=0
    float l = 0.f;
#pragma unroll
    for (int kt = 0; kt < NKT; ++kt) {
      float e = __expf(sreg[kt][r] - mc);
      sreg[kt][r] = e;                   // reuse in pass 2: p = e * Cr
      l += e;
    }
#pragma unroll
    for (int off = 1; off < 16; off <<= 1) l += __shfl_xor(l, off, 64);
    if (col == 0) {
      partM[wave * 16 + quad * 4 + r] = Mw[r];
      partL[wave * 16 + quad * 4 + r] = l;
    }
  }
  __syncthreads();
  if (tid < TQ) {
    float M = -INFINITY, L = 0.f;
#pragma unroll
    for (int w = 0; w < 4; ++w) {
      float m_ = partM[w * 16 + tid], l_ = partL[w * 16 + tid];
      float mn = fmaxf(M, m_);
      if (mn != -INFINITY) {
        L = L * __expf(M - mn) + l_ * __expf(m_ - mn);
        M = mn;
      }
    }
    rowM[tid] = fmaxf(M, -1e30f);
    rowS[tid] = (QM[b * SLQ + q0 + tid] && L > 0.f) ? (1.f / L) : 0.f;
  }
  __syncthreads();
#pragma unroll
  for (int r = 0; r < 4; ++r)
    Cr[r] = __expf(fmaxf(Mw[r], -1e30f) - rowM[quad * 4 + r]) * rowS[quad * 4 + r];

  // ====== Pass 2 (barrier-free): 8 steps of 2 tiles, V via private LDS =====
  float* outp = OUT_P + mbase + (size_t)(quad * 4) * SLK + wave * 16 + col;

  f32x4 acco[4] = {{0.f,0.f,0.f,0.f},{0.f,0.f,0.f,0.f},
                   {0.f,0.f,0.f,0.f},{0.f,0.f,0.f,0.f}};
#pragma unroll
  for (int st = 0; st < 8; ++st) {
    const int kt0 = st * 2, kt1 = kt0 + 1;
    // stage V rows (32: tile kt0 then kt1) into private slice
#pragma unroll
    for (int j = 0; j < 8; ++j)
      *(u16x4*)&Vw[(j * 4 + lrow) * VSTR + lc4] = cvt4(vreg[j]);

    // p for both tiles; P slice layout: row q, cols [0..15]=kt0, [16..31]=kt1
    float p0[4], p1[4];
#pragma unroll
    for (int r = 0; r < 4; ++r) {
      p0[r] = sreg[kt0][r] * Cr[r];
      p1[r] = sreg[kt1][r] * Cr[r];
      Pw[(quad * 4 + r) * PSTR + col]      = f2bf(p0[r]);
      Pw[(quad * 4 + r) * PSTR + 16 + col] = f2bf(p1[r]);
    }
#pragma unroll
    for (int r = 0; r < 4; ++r) {
      outp[(size_t)r * SLK + kt0 * TK] = p0[r];
      outp[(size_t)r * SLK + kt1 * TK] = p1[r];
    }

    // prefetch next step's V
    if (st < 7) {
#pragma unroll
      for (int j = 0; j < 8; ++j)
        vreg[j] = vb4[(size_t)((st * 2 + 2 + (j >> 2)) * TK + wave * 16 + (j & 3) * 4 + lrow) * 16
                      + col];
    }

    // A = P[q=col][kk=quad*8+j]; B = V[kk=quad*8+j][d=n0*16+col]
    bf16x8 ap = __builtin_bit_cast(bf16x8, *(const u16x8*)&Pw[col * PSTR + quad * 8]);
#pragma unroll
    for (int n0 = 0; n0 < 4; ++n0) {
      u16x8 rv;
#pragma unroll
      for (int j = 0; j < 8; ++j)
        rv[j] = Vw[(quad * 8 + j) * VSTR + n0 * 16 + col];
      acco[n0] = __builtin_amdgcn_mfma_f32_16x16x32_bf16(
          ap, __builtin_bit_cast(bf16x8, rv), acco[n0], 0, 0, 0);
    }
  }

  // ====== final O: per-wave partial -> LDS (aliases dead V) -> reduce ======
#pragma unroll
  for (int n0 = 0; n0 < 4; ++n0)
#pragma unroll
    for (int r = 0; r < 4; ++r)
      Ow[(quad * 4 + r) * OSTR + n0 * 16 + col] = acco[n0][r];
  __syncthreads();
  {
    const int qq = tid >> 4, dd = (tid & 15) * 4;
    f32x4 s = {0.f, 0.f, 0.f, 0.f};
#pragma unroll
    for (int w = 0; w < 4; ++w) {
      const float* Os = (const float*)(RAW + w * (32 * VSTR * 2));
      s += *(const f32x4*)&Os[(qq & 15) * OSTR + dd + (qq >> 4) * 0];
    }
    *(f32x4*)&OUT_AV[((size_t)b * SLQ + q0 + (qq & 15)) * DH + dd] = s;
  }
}

extern "C" void kernel_launch(void* const* d_in, const int* in_sizes, int n_in,
                              void* d_out, int out_size, void* d_ws, size_t ws_size,
                              hipStream_t stream) {
  const float* q  = (const float*)d_in[0];
  const float* k  = (const float*)d_in[1];
  const float* v  = (const float*)d_in[2];
  const int*   qm = (const int*)d_in[3];
  const int*   km = (const int*)d_in[4];
  const int*   mk = (const int*)d_in[5];
  float* out_av = (float*)d_out;                          // [B,LQ,D]
  float* out_p  = out_av + (size_t)NB * SLQ * DH;         // [B,LQ,LK]
  sdpa_fused<<<dim3(NB * (SLQ / TQ)), dim3(256), 0, stream>>>(q, k, v, qm, km, mk, out_av, out_p);
}

// Round 3
// 609.195 us; speedup vs baseline: 1.0962x; 1.0266x over previous
//
#include <hip/hip_runtime.h>
#include <hip/hip_bf16.h>

// Fused masked SDPA: B=64, LQ=LK=1024, D=64, temperature=8.
// R6 = R5 + hand-software-pipelined pass 1 (the R3 trick, minus R3's LDS).
//  - Pass 1: direct-global K B-frags, K prefetched 1 tile ahead (L2-hot),
//    masks prefetched 2 tiles ahead (268MB HBM-cold stream, ~900cy latency;
//    they are consumed after the MFMA so depth-2 is free). R5 left these
//    loads in-loop and the compiler scheduled them just-before-use ->
//    one memory round-trip serialized per kt tile. That was the 290us.
//  - Softmax: registered S, max-then-sum, ONE exp pass (e reused as p=e*Cr).
//  - Pass 2: V staged through wave-private LDS slice, prefetched one step
//    ahead (proven R3 structure); P transpose via wave-private LDS slice.
//  - Plain write-back stores (nontemporal caused partial-line RMW in R4).
//  - hw v_cvt bf16, Q pre-scaled by 1/8 (exact).

#define NB   64
#define SLQ  1024
#define SLK  1024
#define DH   64
#define TQ   16
#define TK   64
#define NKT  16
#define VSTR 76   // V slice row stride (u16): 152B -> column reads 2-way max
#define PSTR 40   // P slice row stride (u16): 80B, 16B-aligned for b128
#define OSTR 68   // O partial row stride (f32): 2-way max on writes

typedef __attribute__((ext_vector_type(4))) float          f32x4;
typedef __attribute__((ext_vector_type(8))) __bf16         bf16x8;
typedef __attribute__((ext_vector_type(8))) unsigned short u16x8;
typedef __attribute__((ext_vector_type(4))) unsigned short u16x4;

static __device__ __forceinline__ unsigned short f2bf(float f) {
  return __builtin_bit_cast(unsigned short, (__bf16)f);   // hw cvt, RTNE
}
static __device__ __forceinline__ bf16x8 cvt8(f32x4 a, f32x4 b) {
  bf16x8 r;
#pragma unroll
  for (int i = 0; i < 4; ++i) { r[i] = (__bf16)a[i]; r[i + 4] = (__bf16)b[i]; }
  return r;
}
static __device__ __forceinline__ u16x4 cvt4(f32x4 v) {
  u16x4 h;
#pragma unroll
  for (int i = 0; i < 4; ++i) h[i] = f2bf(v[i]);
  return h;
}

__global__ __launch_bounds__(256, 3) void sdpa_fused(
    const float* __restrict__ Q, const float* __restrict__ K,
    const float* __restrict__ V, const int* __restrict__ QM,
    const int* __restrict__ KM, const int* __restrict__ MSK,
    float* __restrict__ OUT_AV, float* __restrict__ OUT_P) {
  // XCD swizzle: co-schedule same-batch blocks on one XCD for K/V L2 reuse
  const int g    = blockIdx.x;
  const int slot = g >> 3;
  const int b    = ((slot >> 6) << 3) | (g & 7);
  const int q0   = (slot & 63) * TQ;

  const int tid  = threadIdx.x;
  const int wave = tid >> 6;
  const int lane = tid & 63;
  const int col  = lane & 15;
  const int quad = lane >> 4;
  const int lrow = quad;             // staging row subgroup
  const int lc4  = col * 4;          // staging column (x4 elements)

  // LDS: [0,19456): per-wave union of V slice (4864 B) / O partial (4352 B)
  //      [19456,24576): per-wave P slice (1280 B)
  //      [24576,25216): softmax stats
  __shared__ __align__(16) unsigned char RAW[25216];
  unsigned short* Vw = (unsigned short*)(RAW + wave * (32 * VSTR * 2));
  float*          Ow = (float*)(RAW + wave * (32 * VSTR * 2));
  unsigned short* Pw = (unsigned short*)(RAW + 19456) + wave * (16 * PSTR);
  float* partM = (float*)(RAW + 24576);
  float* partL = partM + 64;
  float* rowM  = partL + 64;
  float* rowS  = rowM + 16;

  const size_t mbase = ((size_t)b * SLQ + q0) * SLK;
  const f32x4* vb4 = (const f32x4*)(V + (size_t)b * SLK * DH);

  // ---- Q A-frags from global, pre-scaled by 1/8 (exact exponent shift) ----
  const float* qp = Q + ((size_t)b * SLQ + q0 + col) * DH + quad * 8;
  bf16x8 aq0, aq1;
  {
    f32x4 a = *(const f32x4*)qp        * 0.125f;
    f32x4 c = *(const f32x4*)(qp + 4)  * 0.125f;
    f32x4 d = *(const f32x4*)(qp + 32) * 0.125f;
    f32x4 e = *(const f32x4*)(qp + 36) * 0.125f;
    aq0 = cvt8(a, c);
    aq1 = cvt8(d, e);
  }

  // =================== Pass 1: S = (Q/8)K^T, pipelined global frags ========
  const float* kp  = K + ((size_t)b * SLK + wave * 16 + col) * DH + quad * 8;
  const int*   kmp = KM + b * SLK + wave * 16 + col;
  const int*   mkp = MSK + mbase + (size_t)(quad * 4) * SLK + wave * 16 + col;

  // prologue: K tile 0; masks tiles 0 and 1 (mask stream is HBM-cold)
  f32x4 kreg[4];
  kreg[0] = *(const f32x4*)kp;
  kreg[1] = *(const f32x4*)(kp + 4);
  kreg[2] = *(const f32x4*)(kp + 32);
  kreg[3] = *(const f32x4*)(kp + 36);
  int km0 = kmp[0], km1 = kmp[TK];
  int ms0[4], ms1[4];
#pragma unroll
  for (int r = 0; r < 4; ++r) {
    ms0[r] = mkp[(size_t)r * SLK];
    ms1[r] = mkp[(size_t)r * SLK + TK];
  }

  float sreg[NKT][4];
#pragma unroll
  for (int kt = 0; kt < NKT; ++kt) {
    // consume current K regs into bf16 frags, then overwrite with kt+1
    bf16x8 bk0 = cvt8(kreg[0], kreg[1]);
    bf16x8 bk1 = cvt8(kreg[2], kreg[3]);
    if (kt < NKT - 1) {
      const float* kq = kp + (size_t)(kt + 1) * (TK * DH);
      kreg[0] = *(const f32x4*)kq;
      kreg[1] = *(const f32x4*)(kq + 4);
      kreg[2] = *(const f32x4*)(kq + 32);
      kreg[3] = *(const f32x4*)(kq + 36);
    }
    // prefetch masks for kt+2 (consumed after the MFMAs below)
    int km2 = 0, ms2[4] = {0, 0, 0, 0};
    if (kt < NKT - 2) {
      km2 = kmp[(kt + 2) * TK];
#pragma unroll
      for (int r = 0; r < 4; ++r)
        ms2[r] = mkp[(size_t)r * SLK + (kt + 2) * TK];
    }

    f32x4 acc = {0.f, 0.f, 0.f, 0.f};
    acc = __builtin_amdgcn_mfma_f32_16x16x32_bf16(aq0, bk0, acc, 0, 0, 0);
    acc = __builtin_amdgcn_mfma_f32_16x16x32_bf16(aq1, bk1, acc, 0, 0, 0);

#pragma unroll
    for (int r = 0; r < 4; ++r)
      sreg[kt][r] = (km0 && ms0[r]) ? acc[r] : -INFINITY;

    km0 = km1; km1 = km2;
#pragma unroll
    for (int r = 0; r < 4; ++r) { ms0[r] = ms1[r]; ms1[r] = ms2[r]; }
  }

  // prefetch V step 0 (2 tiles x this wave's 16 rows) during stats phase
  f32x4 vreg[8];
#pragma unroll
  for (int j = 0; j < 8; ++j)
    vreg[j] = vb4[(size_t)((j >> 2) * TK + wave * 16 + (j & 3) * 4 + lrow) * 16 + col];

  // ====== stats: max over registers -> butterfly -> one exp pass -> sum ====
  float Mw[4], Cr[4];
#pragma unroll
  for (int r = 0; r < 4; ++r) {
    float m = sreg[0][r];
#pragma unroll
    for (int kt = 1; kt < NKT; ++kt) m = fmaxf(m, sreg[kt][r]);
#pragma unroll
    for (int off = 1; off < 16; off <<= 1) m = fmaxf(m, __shfl_xor(m, off, 64));
    Mw[r] = m;
    const float mc = fmaxf(m, -1e30f);   // all-masked guard: exp(-inf-mc)=0
    float l = 0.f;
#pragma unroll
    for (int kt = 0; kt < NKT; ++kt) {
      float e = __expf(sreg[kt][r] - mc);
      sreg[kt][r] = e;                   // reuse in pass 2: p = e * Cr
      l += e;
    }
#pragma unroll
    for (int off = 1; off < 16; off <<= 1) l += __shfl_xor(l, off, 64);
    if (col == 0) {
      partM[wave * 16 + quad * 4 + r] = Mw[r];
      partL[wave * 16 + quad * 4 + r] = l;
    }
  }
  __syncthreads();
  if (tid < TQ) {
    float M = -INFINITY, L = 0.f;
#pragma unroll
    for (int w = 0; w < 4; ++w) {
      float m_ = partM[w * 16 + tid], l_ = partL[w * 16 + tid];
      float mn = fmaxf(M, m_);
      if (mn != -INFINITY) {
        L = L * __expf(M - mn) + l_ * __expf(m_ - mn);
        M = mn;
      }
    }
    rowM[tid] = fmaxf(M, -1e30f);
    rowS[tid] = (QM[b * SLQ + q0 + tid] && L > 0.f) ? (1.f / L) : 0.f;
  }
  __syncthreads();
#pragma unroll
  for (int r = 0; r < 4; ++r)
    Cr[r] = __expf(fmaxf(Mw[r], -1e30f) - rowM[quad * 4 + r]) * rowS[quad * 4 + r];

  // ====== Pass 2 (barrier-free): 8 steps of 2 tiles, V via private LDS =====
  float* outp = OUT_P + mbase + (size_t)(quad * 4) * SLK + wave * 16 + col;

  f32x4 acco[4] = {{0.f,0.f,0.f,0.f},{0.f,0.f,0.f,0.f},
                   {0.f,0.f,0.f,0.f},{0.f,0.f,0.f,0.f}};
#pragma unroll
  for (int st = 0; st < 8; ++st) {
    const int kt0 = st * 2, kt1 = kt0 + 1;
    // stage V rows (32: tile kt0 then kt1) into private slice
#pragma unroll
    for (int j = 0; j < 8; ++j)
      *(u16x4*)&Vw[(j * 4 + lrow) * VSTR + lc4] = cvt4(vreg[j]);

    // p for both tiles; P slice layout: row q, cols [0..15]=kt0, [16..31]=kt1
    float p0[4], p1[4];
#pragma unroll
    for (int r = 0; r < 4; ++r) {
      p0[r] = sreg[kt0][r] * Cr[r];
      p1[r] = sreg[kt1][r] * Cr[r];
      Pw[(quad * 4 + r) * PSTR + col]      = f2bf(p0[r]);
      Pw[(quad * 4 + r) * PSTR + 16 + col] = f2bf(p1[r]);
    }
#pragma unroll
    for (int r = 0; r < 4; ++r) {
      outp[(size_t)r * SLK + kt0 * TK] = p0[r];
      outp[(size_t)r * SLK + kt1 * TK] = p1[r];
    }

    // prefetch next step's V
    if (st < 7) {
#pragma unroll
      for (int j = 0; j < 8; ++j)
        vreg[j] = vb4[(size_t)((st * 2 + 2 + (j >> 2)) * TK + wave * 16 + (j & 3) * 4 + lrow) * 16
                      + col];
    }

    // A = P[q=col][kk=quad*8+j]; B = V[kk=quad*8+j][d=n0*16+col]
    bf16x8 ap = __builtin_bit_cast(bf16x8, *(const u16x8*)&Pw[col * PSTR + quad * 8]);
#pragma unroll
    for (int n0 = 0; n0 < 4; ++n0) {
      u16x8 rv;
#pragma unroll
      for (int j = 0; j < 8; ++j)
        rv[j] = Vw[(quad * 8 + j) * VSTR + n0 * 16 + col];
      acco[n0] = __builtin_amdgcn_mfma_f32_16x16x32_bf16(
          ap, __builtin_bit_cast(bf16x8, rv), acco[n0], 0, 0, 0);
    }
  }

  // ====== final O: per-wave partial -> LDS (aliases dead V) -> reduce ======
#pragma unroll
  for (int n0 = 0; n0 < 4; ++n0)
#pragma unroll
    for (int r = 0; r < 4; ++r)
      Ow[(quad * 4 + r) * OSTR + n0 * 16 + col] = acco[n0][r];
  __syncthreads();
  {
    const int qq = tid >> 4, dd = (tid & 15) * 4;
    f32x4 s = {0.f, 0.f, 0.f, 0.f};
#pragma unroll
    for (int w = 0; w < 4; ++w) {
      const float* Os = (const float*)(RAW + w * (32 * VSTR * 2));
      s += *(const f32x4*)&Os[qq * OSTR + dd];
    }
    *(f32x4*)&OUT_AV[((size_t)b * SLQ + q0 + qq) * DH + dd] = s;
  }
}

extern "C" void kernel_launch(void* const* d_in, const int* in_sizes, int n_in,
                              void* d_out, int out_size, void* d_ws, size_t ws_size,
                              hipStream_t stream) {
  const float* q  = (const float*)d_in[0];
  const float* k  = (const float*)d_in[1];
  const float* v  = (const float*)d_in[2];
  const int*   qm = (const int*)d_in[3];
  const int*   km = (const int*)d_in[4];
  const int*   mk = (const int*)d_in[5];
  float* out_av = (float*)d_out;                          // [B,LQ,D]
  float* out_p  = out_av + (size_t)NB * SLQ * DH;         // [B,LQ,LK]
  sdpa_fused<<<dim3(NB * (SLQ / TQ)), dim3(256), 0, stream>>>(q, k, v, qm, km, mk, out_av, out_p);
}